// Round 1
// baseline (1529.633 us; speedup 1.0000x reference)
//
#include <hip/hip_runtime.h>
#include <cstddef>

#define BATCH 2048
#define DM 2048
#define DI 4096
#define DS 16
#define LN_EPS 1e-5f

typedef __bf16 bf16x8 __attribute__((ext_vector_type(8)));
typedef float f32x4 __attribute__((ext_vector_type(4)));
typedef unsigned short u16;

// RNE float -> bf16 (bit trick, valid for all finite values)
__device__ __forceinline__ u16 f2bf(float f) {
  unsigned u = __float_as_uint(f);
  u += 0x7fffu + ((u >> 16) & 1u);
  return (u16)(u >> 16);
}
__device__ __forceinline__ void split1(float f, u16& h, u16& l) {
  h = f2bf(f);
  float hf = __uint_as_float((unsigned)h << 16);
  l = f2bf(f - hf);
}

#define GLOAD16(g, l)                                                          \
  __builtin_amdgcn_global_load_lds(                                            \
      (const __attribute__((address_space(1))) unsigned int*)(g),              \
      (__attribute__((address_space(3))) unsigned int*)(l), 16, 0, 0)

// ---------------- LayerNorm + hi/lo bf16 split output ----------------
__global__ __launch_bounds__(256) void ln_split_kernel(
    const float* __restrict__ x, const float* __restrict__ gamma,
    const float* __restrict__ beta, u16* __restrict__ xnh,
    u16* __restrict__ xnl) {
  int row = blockIdx.x;
  int t = threadIdx.x;
  const float4* xr = (const float4*)(x + (size_t)row * DM);
  float4 v0 = xr[t];
  float4 v1 = xr[t + 256];
  float s  = v0.x + v0.y + v0.z + v0.w + v1.x + v1.y + v1.z + v1.w;
  float ss = v0.x*v0.x + v0.y*v0.y + v0.z*v0.z + v0.w*v0.w
           + v1.x*v1.x + v1.y*v1.y + v1.z*v1.z + v1.w*v1.w;
#pragma unroll
  for (int off = 32; off >= 1; off >>= 1) {
    s  += __shfl_down(s, off);
    ss += __shfl_down(ss, off);
  }
  __shared__ float red[8];
  int wave = t >> 6;
  if ((t & 63) == 0) { red[wave] = s; red[4 + wave] = ss; }
  __syncthreads();
  if (t == 0) {
    float fs  = red[0] + red[1] + red[2] + red[3];
    float fss = red[4] + red[5] + red[6] + red[7];
    float mu  = fs * (1.0f / DM);
    red[0] = mu;
    red[1] = rsqrtf(fss * (1.0f / DM) - mu * mu + LN_EPS);
  }
  __syncthreads();
  float mu = red[0], rstd = red[1];
  const float4* g  = (const float4*)gamma;
  const float4* be = (const float4*)beta;
  float4 g0 = g[t], g1 = g[t + 256], b0 = be[t], b1 = be[t + 256];
  float o[8];
  o[0] = (v0.x - mu) * rstd * g0.x + b0.x;
  o[1] = (v0.y - mu) * rstd * g0.y + b0.y;
  o[2] = (v0.z - mu) * rstd * g0.z + b0.z;
  o[3] = (v0.w - mu) * rstd * g0.w + b0.w;
  o[4] = (v1.x - mu) * rstd * g1.x + b1.x;
  o[5] = (v1.y - mu) * rstd * g1.y + b1.y;
  o[6] = (v1.z - mu) * rstd * g1.z + b1.z;
  o[7] = (v1.w - mu) * rstd * g1.w + b1.w;
  ushort4 h0, l0, h1, l1;
  split1(o[0], h0.x, l0.x); split1(o[1], h0.y, l0.y);
  split1(o[2], h0.z, l0.z); split1(o[3], h0.w, l0.w);
  split1(o[4], h1.x, l1.x); split1(o[5], h1.y, l1.y);
  split1(o[6], h1.z, l1.z); split1(o[7], h1.w, l1.w);
  ushort4* hr = (ushort4*)(xnh + (size_t)row * DM);
  ushort4* lr = (ushort4*)(xnl + (size_t)row * DM);
  hr[t] = h0; hr[t + 256] = h1;
  lr[t] = l0; lr[t + 256] = l1;
}

// ---------------- fp32 -> (hi,lo) bf16 split for weight matrices ----------
__global__ __launch_bounds__(256) void split_kernel(const float* __restrict__ in,
                                                    u16* __restrict__ hi,
                                                    u16* __restrict__ lo,
                                                    int n4) {
  int i = blockIdx.x * 256 + threadIdx.x;
  if (i >= n4) return;
  float4 v = ((const float4*)in)[i];
  ushort4 h, l;
  split1(v.x, h.x, l.x); split1(v.y, h.y, l.y);
  split1(v.z, h.z, l.z); split1(v.w, h.w, l.w);
  ((ushort4*)hi)[i] = h;
  ((ushort4*)lo)[i] = l;
}

// ---------------- split-bf16 MFMA GEMM: C[m,n] = sum_k A[m,k]*B[n,k] ------
// A,B given as (hi,lo) bf16 row-major MxK / NxK. Tile BM=128 x BN, BK=32.
// 4 waves (2x2), wave tile 64 x (NF*16). 3 MFMA per frag pair (bf16x3).
template <int BN>
__global__ __launch_bounds__(256) void gemm_split(
    const u16* __restrict__ Ah, const u16* __restrict__ Al,
    const u16* __restrict__ Bh, const u16* __restrict__ Bl,
    float* __restrict__ C, const float* __restrict__ resid,
    int M, int N, int K) {
  (void)M;
  constexpr int NF = BN / 32;       // B frags per wave
  constexpr int BPART = BN * 64;    // bytes per B part tile ([BN][32] bf16)
  __shared__ alignas(16) char lds[16384 + 2 * BPART];
  // layout: Ah [0,8K), Al [8K,16K), Bh [16K,16K+BPART), Bl [16K+BPART,...)

  const int t = threadIdx.x;
  const int lane = t & 63;
  const int w = t >> 6;
  const int bm = blockIdx.y << 7;
  const int bn = blockIdx.x * BN;
  const int wr = (w >> 1) << 6;
  const int wc = (w & 1) * (NF * 16);

  // staging: chunk q (16B) -> row=q>>2, slot=q&3, logical kchunk = slot^(row&3)
  const int sr = t >> 2;                       // 0..63
  const int kc_s = (t & 3) ^ (sr & 3);
  const size_t oA0 = (size_t)(bm + sr) * K + kc_s * 8;
  const size_t oA1 = oA0 + (size_t)64 * K;
  const size_t oB0 = (size_t)(bn + sr) * K + kc_s * 8;
  const size_t oB1 = oB0 + (size_t)64 * K;     // only used when BN==128
  char* l0 = lds + (w << 10);                  // wave-uniform LDS dest base

  // fragment LDS offsets (loop-invariant; same XOR swizzle as staging)
  const int lrow = lane & 15;
  const int kq = lane >> 4;
  const int ksw = ((kq ^ (lrow & 3)) << 4);
  int foA[4], foB[NF];
#pragma unroll
  for (int i = 0; i < 4; ++i) foA[i] = (wr + i * 16 + lrow) * 64 + ksw;
#pragma unroll
  for (int j = 0; j < NF; ++j) foB[j] = (wc + j * 16 + lrow) * 64 + ksw;

  f32x4 acc[4][NF];
#pragma unroll
  for (int i = 0; i < 4; ++i)
#pragma unroll
    for (int j = 0; j < NF; ++j) acc[i][j] = (f32x4){0.f, 0.f, 0.f, 0.f};

  for (int k0 = 0; k0 < K; k0 += 32) {
    __syncthreads();  // previous tile fully consumed
    GLOAD16(Ah + oA0 + k0, l0);
    GLOAD16(Ah + oA1 + k0, l0 + 4096);
    GLOAD16(Al + oA0 + k0, l0 + 8192);
    GLOAD16(Al + oA1 + k0, l0 + 8192 + 4096);
    GLOAD16(Bh + oB0 + k0, l0 + 16384);
    GLOAD16(Bl + oB0 + k0, l0 + 16384 + BPART);
    if constexpr (BN == 128) {
      GLOAD16(Bh + oB1 + k0, l0 + 16384 + 4096);
      GLOAD16(Bl + oB1 + k0, l0 + 16384 + BPART + 4096);
    }
    __syncthreads();  // compiler drains vmcnt before barrier -> tile ready

    bf16x8 ah[4], al4[4], bh[NF], bl4[NF];
#pragma unroll
    for (int i = 0; i < 4; ++i) {
      ah[i]  = *(const bf16x8*)(lds + foA[i]);
      al4[i] = *(const bf16x8*)(lds + 8192 + foA[i]);
    }
#pragma unroll
    for (int j = 0; j < NF; ++j) {
      bh[j]  = *(const bf16x8*)(lds + 16384 + foB[j]);
      bl4[j] = *(const bf16x8*)(lds + 16384 + BPART + foB[j]);
    }
#pragma unroll
    for (int i = 0; i < 4; ++i)
#pragma unroll
      for (int j = 0; j < NF; ++j) {
        acc[i][j] = __builtin_amdgcn_mfma_f32_16x16x32_bf16(ah[i],  bh[j],  acc[i][j], 0, 0, 0);
        acc[i][j] = __builtin_amdgcn_mfma_f32_16x16x32_bf16(ah[i],  bl4[j], acc[i][j], 0, 0, 0);
        acc[i][j] = __builtin_amdgcn_mfma_f32_16x16x32_bf16(al4[i], bh[j],  acc[i][j], 0, 0, 0);
      }
  }

  // epilogue: C/D layout col = lane&15, row = (lane>>4)*4 + reg  [m89-verified]
  const int rb = bm + wr + (kq << 2);
  const int cb = bn + wc + lrow;
#pragma unroll
  for (int i = 0; i < 4; ++i) {
#pragma unroll
    for (int r = 0; r < 4; ++r) {
      const size_t ro = (size_t)(rb + i * 16 + r) * N + cb;
#pragma unroll
      for (int j = 0; j < NF; ++j) {
        float v = acc[i][j][r];
        if (resid) v += resid[ro + j * 16];
        C[ro + j * 16] = v;
      }
    }
  }
}

// ---------------- xp = x_main @ W_xp.T : (B, 33), K = DI ----------------
__global__ __launch_bounds__(256) void xp_kernel(const float* __restrict__ xz,
                                                 const float* __restrict__ W_xp,
                                                 float* __restrict__ xp) {
  int b = blockIdx.x;
  int t = threadIdx.x;
  const float* xm = xz + ((size_t)b << 13);  // x_main = xz[b, 0:4096]
  float acc[33];
#pragma unroll
  for (int j = 0; j < 33; ++j) acc[j] = 0.f;
  for (int k = t; k < DI; k += 256) {
    float xv = xm[k];
#pragma unroll
    for (int j = 0; j < 33; ++j)
      acc[j] = fmaf(xv, W_xp[j * DI + k], acc[j]);
  }
#pragma unroll
  for (int j = 0; j < 33; ++j) {
#pragma unroll
    for (int off = 32; off >= 1; off >>= 1)
      acc[j] += __shfl_down(acc[j], off);
  }
  __shared__ float red[4][33];
  int wave = t >> 6, lane = t & 63;
  if (lane == 0) {
#pragma unroll
    for (int j = 0; j < 33; ++j) red[wave][j] = acc[j];
  }
  __syncthreads();
  if (t < 33)
    xp[b * 33 + t] = red[0][t] + red[1][t] + red[2][t] + red[3][t];
}

// ---------------- SSM state update + gate (split bf16 y_gated out) --------
__global__ __launch_bounds__(256) void ssm_kernel(const float* __restrict__ xz,
                                                  const float* __restrict__ xp,
                                                  const float* __restrict__ h,
                                                  const float* __restrict__ log_A,
                                                  const float* __restrict__ dt_bias,
                                                  const float* __restrict__ D_param,
                                                  float* __restrict__ h_new,
                                                  u16* __restrict__ ygh,
                                                  u16* __restrict__ ygl) {
  size_t idx = (size_t)blockIdx.x * 256 + threadIdx.x;  // b*DI + d
  int b = (int)(idx >> 12);
  int d = (int)(idx & 4095);
  const float* xrow = xz + ((size_t)b << 13);
  float xm = xrow[d];
  float zv = xrow[4096 + d];
  const float* xpb = xp + b * 33;
  float tt = xpb[32] + dt_bias[d];
  float delta = (tt > 0.f) ? tt + log1pf(__expf(-tt)) : log1pf(__expf(tt));
  float dxm = delta * xm;
  const float4* hp  = (const float4*)(h + (idx << 4));
  const float4* lap = (const float4*)(log_A + ((size_t)d << 4));
  float4* hop = (float4*)(h_new + (idx << 4));
  float y = 0.f;
#pragma unroll
  for (int q = 0; q < 4; ++q) {
    float4 hv = hp[q];
    float4 la = lap[q];
    float B0 = xpb[q * 4 + 0], B1 = xpb[q * 4 + 1];
    float B2 = xpb[q * 4 + 2], B3 = xpb[q * 4 + 3];
    float C0 = xpb[16 + q * 4 + 0], C1 = xpb[16 + q * 4 + 1];
    float C2 = xpb[16 + q * 4 + 2], C3 = xpb[16 + q * 4 + 3];
    float4 hn;
    hn.x = __expf(-delta * __expf(la.x)) * hv.x + B0 * dxm;
    hn.y = __expf(-delta * __expf(la.y)) * hv.y + B1 * dxm;
    hn.z = __expf(-delta * __expf(la.z)) * hv.z + B2 * dxm;
    hn.w = __expf(-delta * __expf(la.w)) * hv.w + B3 * dxm;
    y = fmaf(hn.x, C0, y);
    y = fmaf(hn.y, C1, y);
    y = fmaf(hn.z, C2, y);
    y = fmaf(hn.w, C3, y);
    hop[q] = hn;
  }
  y = fmaf(D_param[d], xm, y);
  float sig = 1.0f / (1.0f + __expf(-zv));
  float yv = y * (zv * sig);
  u16 hs, ls;
  split1(yv, hs, ls);
  ygh[idx] = hs;
  ygl[idx] = ls;
}

extern "C" void kernel_launch(void* const* d_in, const int* in_sizes, int n_in,
                              void* d_out, int out_size, void* d_ws, size_t ws_size,
                              hipStream_t stream) {
  const float* x       = (const float*)d_in[0];
  const float* h       = (const float*)d_in[1];
  const float* W_in    = (const float*)d_in[2];
  const float* W_xp    = (const float*)d_in[3];
  const float* log_A   = (const float*)d_in[4];
  const float* dt_bias = (const float*)d_in[5];
  const float* D_param = (const float*)d_in[6];
  const float* W_out   = (const float*)d_in[7];
  const float* gamma   = (const float*)d_in[8];
  const float* beta    = (const float*)d_in[9];

  float* out   = (float*)d_out;
  float* y_out = out;                         // (BATCH, DM)
  float* h_out = out + (size_t)BATCH * DM;    // (BATCH, DI, DS)

  // workspace (exactly the previous 100.9 MB footprint):
  float* ws  = (float*)d_ws;
  float* xz  = ws;                                  // (BATCH, 2*DI) fp32
  float* xpb = xz + (size_t)BATCH * 2 * DI;         // (BATCH, 33)
  u16*  ygh  = (u16*)(xpb + (size_t)BATCH * 33);    // (BATCH, DI) bf16 hi
  u16*  ygl  = ygh + (size_t)BATCH * DI;            // (BATCH, DI) bf16 lo

  // scratch regions inside d_out (dead at the time they're used):
  u16* xnh = (u16*)y_out;                           // LN out hi (y region)
  u16* xnl = xnh + (size_t)BATCH * DM;              // LN out lo
  u16* Wih = (u16*)h_out;                           // W_in split (h region,
  u16* Wil = Wih + (size_t)2 * DI * DM;             //  free until ssm writes)
  // W_out split goes into the xz region (dead after ssm):
  u16* Woh = (u16*)xz;
  u16* Wol = Woh + (size_t)DM * DI;

  // 1. LN + split
  ln_split_kernel<<<BATCH, 256, 0, stream>>>(x, gamma, beta, xnh, xnl);
  // 2. split W_in
  split_kernel<<<(2 * DI * DM / 4) / 256, 256, 0, stream>>>(
      W_in, Wih, Wil, 2 * DI * DM / 4);
  // 3. GEMM1: xz = xn @ W_in.T   (M=2048, N=8192, K=2048)
  gemm_split<128><<<dim3((2 * DI) / 128, BATCH / 128), 256, 0, stream>>>(
      xnh, xnl, Wih, Wil, xz, nullptr, BATCH, 2 * DI, DM);
  // 4. xp projection
  xp_kernel<<<BATCH, 256, 0, stream>>>(xz, W_xp, xpb);
  // 5. SSM (writes h_out, overwriting the dead W_in split; emits split yg)
  ssm_kernel<<<(BATCH * DI) / 256, 256, 0, stream>>>(
      xz, xpb, h, log_A, dt_bias, D_param, h_out, ygh, ygl);
  // 6. split W_out into the now-dead xz region
  split_kernel<<<(DM * DI / 4) / 256, 256, 0, stream>>>(
      W_out, Woh, Wol, DM * DI / 4);
  // 7. GEMM2: y = yg @ W_out.T + x   (M=2048, N=2048, K=4096), 128x64 tiles
  gemm_split<64><<<dim3(DM / 64, BATCH / 128), 256, 0, stream>>>(
      ygh, ygl, Woh, Wol, y_out, x, BATCH, DM, DI);
}

// Round 2
// 1428.584 us; speedup vs baseline: 1.0707x; 1.0707x over previous
//
#include <hip/hip_runtime.h>
#include <cstddef>

#define BATCH 2048
#define DM 2048
#define DI 4096
#define DS 16
#define LN_EPS 1e-5f

typedef __bf16 bf16x8 __attribute__((ext_vector_type(8)));
typedef float f32x4 __attribute__((ext_vector_type(4)));
typedef unsigned short u16;

// RNE float -> bf16 (bit trick, valid for all finite values)
__device__ __forceinline__ u16 f2bf(float f) {
  unsigned u = __float_as_uint(f);
  u += 0x7fffu + ((u >> 16) & 1u);
  return (u16)(u >> 16);
}
__device__ __forceinline__ void split1(float f, u16& h, u16& l) {
  h = f2bf(f);
  float hf = __uint_as_float((unsigned)h << 16);
  l = f2bf(f - hf);
}

#define GLOAD16(g, l)                                                          \
  __builtin_amdgcn_global_load_lds(                                            \
      (const __attribute__((address_space(1))) unsigned int*)(g),              \
      (__attribute__((address_space(3))) unsigned int*)(l), 16, 0, 0)

// ---------------- LayerNorm + hi/lo bf16 split output ----------------
__global__ __launch_bounds__(256) void ln_split_kernel(
    const float* __restrict__ x, const float* __restrict__ gamma,
    const float* __restrict__ beta, u16* __restrict__ xnh,
    u16* __restrict__ xnl) {
  int row = blockIdx.x;
  int t = threadIdx.x;
  const float4* xr = (const float4*)(x + (size_t)row * DM);
  float4 v0 = xr[t];
  float4 v1 = xr[t + 256];
  float s  = v0.x + v0.y + v0.z + v0.w + v1.x + v1.y + v1.z + v1.w;
  float ss = v0.x*v0.x + v0.y*v0.y + v0.z*v0.z + v0.w*v0.w
           + v1.x*v1.x + v1.y*v1.y + v1.z*v1.z + v1.w*v1.w;
#pragma unroll
  for (int off = 32; off >= 1; off >>= 1) {
    s  += __shfl_down(s, off);
    ss += __shfl_down(ss, off);
  }
  __shared__ float red[8];
  int wave = t >> 6;
  if ((t & 63) == 0) { red[wave] = s; red[4 + wave] = ss; }
  __syncthreads();
  if (t == 0) {
    float fs  = red[0] + red[1] + red[2] + red[3];
    float fss = red[4] + red[5] + red[6] + red[7];
    float mu  = fs * (1.0f / DM);
    red[0] = mu;
    red[1] = rsqrtf(fss * (1.0f / DM) - mu * mu + LN_EPS);
  }
  __syncthreads();
  float mu = red[0], rstd = red[1];
  const float4* g  = (const float4*)gamma;
  const float4* be = (const float4*)beta;
  float4 g0 = g[t], g1 = g[t + 256], b0 = be[t], b1 = be[t + 256];
  float o[8];
  o[0] = (v0.x - mu) * rstd * g0.x + b0.x;
  o[1] = (v0.y - mu) * rstd * g0.y + b0.y;
  o[2] = (v0.z - mu) * rstd * g0.z + b0.z;
  o[3] = (v0.w - mu) * rstd * g0.w + b0.w;
  o[4] = (v1.x - mu) * rstd * g1.x + b1.x;
  o[5] = (v1.y - mu) * rstd * g1.y + b1.y;
  o[6] = (v1.z - mu) * rstd * g1.z + b1.z;
  o[7] = (v1.w - mu) * rstd * g1.w + b1.w;
  ushort4 h0, l0, h1, l1;
  split1(o[0], h0.x, l0.x); split1(o[1], h0.y, l0.y);
  split1(o[2], h0.z, l0.z); split1(o[3], h0.w, l0.w);
  split1(o[4], h1.x, l1.x); split1(o[5], h1.y, l1.y);
  split1(o[6], h1.z, l1.z); split1(o[7], h1.w, l1.w);
  ushort4* hr = (ushort4*)(xnh + (size_t)row * DM);
  ushort4* lr = (ushort4*)(xnl + (size_t)row * DM);
  hr[t] = h0; hr[t + 256] = h1;
  lr[t] = l0; lr[t + 256] = l1;
}

// ---------------- fp32 -> (hi,lo) bf16 split for weight matrices ----------
__global__ __launch_bounds__(256) void split_kernel(const float* __restrict__ in,
                                                    u16* __restrict__ hi,
                                                    u16* __restrict__ lo,
                                                    int n4) {
  int i = blockIdx.x * 256 + threadIdx.x;
  if (i >= n4) return;
  float4 v = ((const float4*)in)[i];
  ushort4 h, l;
  split1(v.x, h.x, l.x); split1(v.y, h.y, l.y);
  split1(v.z, h.z, l.z); split1(v.w, h.w, l.w);
  ((ushort4*)hi)[i] = h;
  ((ushort4*)lo)[i] = l;
}

// ---------------- split-bf16 MFMA GEMM: C[m,n] = sum_k A[m,k]*B[n,k] ------
// A,B given as (hi,lo) bf16 row-major MxK / NxK. Tile BM=128 x BN, BK=32.
// 4 waves (2x2), wave tile 64 x (NF*16). 3 MFMA per frag pair (bf16x3).
template <int BN>
__global__ __launch_bounds__(256) void gemm_split(
    const u16* __restrict__ Ah, const u16* __restrict__ Al,
    const u16* __restrict__ Bh, const u16* __restrict__ Bl,
    float* __restrict__ C, const float* __restrict__ resid,
    int M, int N, int K) {
  (void)M;
  constexpr int NF = BN / 32;       // B frags per wave
  constexpr int BPART = BN * 64;    // bytes per B part tile ([BN][32] bf16)
  __shared__ alignas(16) char lds[16384 + 2 * BPART];
  // layout: Ah [0,8K), Al [8K,16K), Bh [16K,16K+BPART), Bl [16K+BPART,...)

  const int t = threadIdx.x;
  const int lane = t & 63;
  const int w = t >> 6;

  // XCD-aware bijective block swizzle (grid size % 8 == 0 for both GEMMs)
  const int nbx = gridDim.x;
  const int nwg = nbx * gridDim.y;
  const int bid = blockIdx.y * nbx + blockIdx.x;
  const int swz = (bid & 7) * (nwg >> 3) + (bid >> 3);
  const int bm = (swz / nbx) << 7;
  const int bn = (swz % nbx) * BN;

  const int wr = (w >> 1) << 6;
  const int wc = (w & 1) * (NF * 16);

  // staging: chunk q (16B) -> row=q>>2, slot=q&3, logical kchunk = slot^(row&3)
  const int sr = t >> 2;                       // 0..63
  const int kc_s = (t & 3) ^ (sr & 3);
  const size_t oA0 = (size_t)(bm + sr) * K + kc_s * 8;
  const size_t oA1 = oA0 + (size_t)64 * K;
  const size_t oB0 = (size_t)(bn + sr) * K + kc_s * 8;
  const size_t oB1 = oB0 + (size_t)64 * K;     // only used when BN==128
  char* l0 = lds + (w << 10);                  // wave-uniform LDS dest base

  // fragment LDS offsets (loop-invariant; same XOR swizzle as staging)
  const int lrow = lane & 15;
  const int kq = lane >> 4;
  const int ksw = ((kq ^ (lrow & 3)) << 4);
  int foA[4], foB[NF];
#pragma unroll
  for (int i = 0; i < 4; ++i) foA[i] = (wr + i * 16 + lrow) * 64 + ksw;
#pragma unroll
  for (int j = 0; j < NF; ++j) foB[j] = (wc + j * 16 + lrow) * 64 + ksw;

  f32x4 acc[4][NF];
#pragma unroll
  for (int i = 0; i < 4; ++i)
#pragma unroll
    for (int j = 0; j < NF; ++j) acc[i][j] = (f32x4){0.f, 0.f, 0.f, 0.f};

  for (int k0 = 0; k0 < K; k0 += 32) {
    __syncthreads();  // previous tile fully consumed
    GLOAD16(Ah + oA0 + k0, l0);
    GLOAD16(Ah + oA1 + k0, l0 + 4096);
    GLOAD16(Al + oA0 + k0, l0 + 8192);
    GLOAD16(Al + oA1 + k0, l0 + 8192 + 4096);
    GLOAD16(Bh + oB0 + k0, l0 + 16384);
    GLOAD16(Bl + oB0 + k0, l0 + 16384 + BPART);
    if constexpr (BN == 128) {
      GLOAD16(Bh + oB1 + k0, l0 + 16384 + 4096);
      GLOAD16(Bl + oB1 + k0, l0 + 16384 + BPART + 4096);
    }
    __syncthreads();  // compiler drains vmcnt before barrier -> tile ready

    bf16x8 ah[4], al4[4], bh[NF], bl4[NF];
#pragma unroll
    for (int i = 0; i < 4; ++i) {
      ah[i]  = *(const bf16x8*)(lds + foA[i]);
      al4[i] = *(const bf16x8*)(lds + 8192 + foA[i]);
    }
#pragma unroll
    for (int j = 0; j < NF; ++j) {
      bh[j]  = *(const bf16x8*)(lds + 16384 + foB[j]);
      bl4[j] = *(const bf16x8*)(lds + 16384 + BPART + foB[j]);
    }
#pragma unroll
    for (int i = 0; i < 4; ++i)
#pragma unroll
      for (int j = 0; j < NF; ++j) {
        acc[i][j] = __builtin_amdgcn_mfma_f32_16x16x32_bf16(ah[i],  bh[j],  acc[i][j], 0, 0, 0);
        acc[i][j] = __builtin_amdgcn_mfma_f32_16x16x32_bf16(ah[i],  bl4[j], acc[i][j], 0, 0, 0);
        acc[i][j] = __builtin_amdgcn_mfma_f32_16x16x32_bf16(al4[i], bh[j],  acc[i][j], 0, 0, 0);
      }
  }

  // epilogue: C/D layout col = lane&15, row = (lane>>4)*4 + reg  [m89-verified]
  const int rb = bm + wr + (kq << 2);
  const int cb = bn + wc + lrow;
#pragma unroll
  for (int i = 0; i < 4; ++i) {
#pragma unroll
    for (int r = 0; r < 4; ++r) {
      const size_t ro = (size_t)(rb + i * 16 + r) * N + cb;
#pragma unroll
      for (int j = 0; j < NF; ++j) {
        float v = acc[i][j][r];
        if (resid) v += resid[ro + j * 16];
        C[ro + j * 16] = v;
      }
    }
  }
}

// ---------------- xp = x_main @ W_xp.T : (B, 33), K = DI ----------------
__global__ __launch_bounds__(256) void xp_kernel(const float* __restrict__ xz,
                                                 const float* __restrict__ W_xp,
                                                 float* __restrict__ xp) {
  int b = blockIdx.x;
  int t = threadIdx.x;
  const float* xm = xz + ((size_t)b << 13);  // x_main = xz[b, 0:4096]
  float acc[33];
#pragma unroll
  for (int j = 0; j < 33; ++j) acc[j] = 0.f;
  for (int k = t; k < DI; k += 256) {
    float xv = xm[k];
#pragma unroll
    for (int j = 0; j < 33; ++j)
      acc[j] = fmaf(xv, W_xp[j * DI + k], acc[j]);
  }
#pragma unroll
  for (int j = 0; j < 33; ++j) {
#pragma unroll
    for (int off = 32; off >= 1; off >>= 1)
      acc[j] += __shfl_down(acc[j], off);
  }
  __shared__ float red[4][33];
  int wave = t >> 6, lane = t & 63;
  if (lane == 0) {
#pragma unroll
    for (int j = 0; j < 33; ++j) red[wave][j] = acc[j];
  }
  __syncthreads();
  if (t < 33)
    xp[b * 33 + t] = red[0][t] + red[1][t] + red[2][t] + red[3][t];
}

// ---------------- SSM state update + gate: 4 threads per (b,d) ------------
// lane q = tid&3 owns state-quad q (one float4 of h). Fully coalesced h/h_new.
__global__ __launch_bounds__(256) void ssm_kernel(const float* __restrict__ xz,
                                                  const float* __restrict__ xp,
                                                  const float* __restrict__ h,
                                                  const float* __restrict__ log_A,
                                                  const float* __restrict__ dt_bias,
                                                  const float* __restrict__ D_param,
                                                  float* __restrict__ h_new,
                                                  u16* __restrict__ ygh,
                                                  u16* __restrict__ ygl) {
  size_t tid = (size_t)blockIdx.x * 256 + threadIdx.x;
  size_t g = tid >> 2;                 // b*DI + d
  int q = (int)(tid & 3);
  int b = (int)(g >> 12);
  int d = (int)(g & 4095);
  const float* xrow = xz + ((size_t)b << 13);
  float xm = xrow[d];
  const float* xpb = xp + b * 33;
  float tt = xpb[32] + dt_bias[d];
  // stable softplus
  float delta = (tt > 0.f) ? tt + log1pf(__expf(-tt)) : log1pf(__expf(tt));
  float dxm = delta * xm;
  float4 hv = ((const float4*)h)[g * 4 + q];                 // 16B/lane coalesced
  float4 la = ((const float4*)log_A)[((size_t)d << 2) + q];
  float B0 = xpb[q * 4 + 0], B1 = xpb[q * 4 + 1];
  float B2 = xpb[q * 4 + 2], B3 = xpb[q * 4 + 3];
  float C0 = xpb[16 + q * 4 + 0], C1 = xpb[16 + q * 4 + 1];
  float C2 = xpb[16 + q * 4 + 2], C3 = xpb[16 + q * 4 + 3];
  float4 hn;
  hn.x = __expf(-delta * __expf(la.x)) * hv.x + B0 * dxm;
  hn.y = __expf(-delta * __expf(la.y)) * hv.y + B1 * dxm;
  hn.z = __expf(-delta * __expf(la.z)) * hv.z + B2 * dxm;
  hn.w = __expf(-delta * __expf(la.w)) * hv.w + B3 * dxm;
  ((float4*)h_new)[g * 4 + q] = hn;                          // 16B/lane coalesced
  float y = hn.x * C0;
  y = fmaf(hn.y, C1, y);
  y = fmaf(hn.z, C2, y);
  y = fmaf(hn.w, C3, y);
  // reduce across the 4-lane group
  y += __shfl_xor(y, 1);
  y += __shfl_xor(y, 2);
  if (q == 0) {
    float zv = xrow[4096 + d];
    y = fmaf(D_param[d], xm, y);
    float sig = 1.0f / (1.0f + __expf(-zv));
    float yv = y * (zv * sig);
    u16 hs, ls;
    split1(yv, hs, ls);
    ygh[g] = hs;
    ygl[g] = ls;
  }
}

extern "C" void kernel_launch(void* const* d_in, const int* in_sizes, int n_in,
                              void* d_out, int out_size, void* d_ws, size_t ws_size,
                              hipStream_t stream) {
  const float* x       = (const float*)d_in[0];
  const float* h       = (const float*)d_in[1];
  const float* W_in    = (const float*)d_in[2];
  const float* W_xp    = (const float*)d_in[3];
  const float* log_A   = (const float*)d_in[4];
  const float* dt_bias = (const float*)d_in[5];
  const float* D_param = (const float*)d_in[6];
  const float* W_out   = (const float*)d_in[7];
  const float* gamma   = (const float*)d_in[8];
  const float* beta    = (const float*)d_in[9];

  float* out   = (float*)d_out;
  float* y_out = out;                         // (BATCH, DM)
  float* h_out = out + (size_t)BATCH * DM;    // (BATCH, DI, DS)

  // workspace (exactly the previous 100.9 MB footprint):
  float* ws  = (float*)d_ws;
  float* xz  = ws;                                  // (BATCH, 2*DI) fp32
  float* xpb = xz + (size_t)BATCH * 2 * DI;         // (BATCH, 33)
  u16*  ygh  = (u16*)(xpb + (size_t)BATCH * 33);    // (BATCH, DI) bf16 hi
  u16*  ygl  = ygh + (size_t)BATCH * DI;            // (BATCH, DI) bf16 lo

  // scratch regions inside d_out (dead at the time they're used):
  u16* xnh = (u16*)y_out;                           // LN out hi (y region)
  u16* xnl = xnh + (size_t)BATCH * DM;              // LN out lo
  u16* Wih = (u16*)h_out;                           // W_in split (h region,
  u16* Wil = Wih + (size_t)2 * DI * DM;             //  free until ssm writes)
  // W_out split goes into the xz region (dead after ssm):
  u16* Woh = (u16*)xz;
  u16* Wol = Woh + (size_t)DM * DI;

  // 1. LN + split
  ln_split_kernel<<<BATCH, 256, 0, stream>>>(x, gamma, beta, xnh, xnl);
  // 2. split W_in
  split_kernel<<<(2 * DI * DM / 4) / 256, 256, 0, stream>>>(
      W_in, Wih, Wil, 2 * DI * DM / 4);
  // 3. GEMM1: xz = xn @ W_in.T   (M=2048, N=8192, K=2048)
  gemm_split<128><<<dim3((2 * DI) / 128, BATCH / 128), 256, 0, stream>>>(
      xnh, xnl, Wih, Wil, xz, nullptr, BATCH, 2 * DI, DM);
  // 4. xp projection
  xp_kernel<<<BATCH, 256, 0, stream>>>(xz, W_xp, xpb);
  // 5. SSM (writes h_out, overwriting the dead W_in split; emits split yg)
  ssm_kernel<<<(BATCH * DI * 4) / 256, 256, 0, stream>>>(
      xz, xpb, h, log_A, dt_bias, D_param, h_out, ygh, ygl);
  // 6. split W_out into the now-dead xz region
  split_kernel<<<(DM * DI / 4) / 256, 256, 0, stream>>>(
      W_out, Woh, Wol, DM * DI / 4);
  // 7. GEMM2: y = yg @ W_out.T + x   (M=2048, N=2048, K=4096), 128x64 tiles
  gemm_split<64><<<dim3(DM / 64, BATCH / 128), 256, 0, stream>>>(
      ygh, ygl, Woh, Wol, y_out, x, BATCH, DM, DI);
}